// Round 18
// baseline (1101.333 us; speedup 1.0000x reference)
//
#include <hip/hip_runtime.h>

#define N_ROWS 8192
#define K_CODES 8192
#define D_DIM 512

typedef unsigned long long u64;

// ---------------------------------------------------------------------------
// Kernel 1: x_sq / e_sq, wave-parallel, bit-exact numpy pairwise emulation
// (validated R9-R17). 32 lanes per row; shfl_xor tree = numpy's add order.
// ---------------------------------------------------------------------------
__global__ __launch_bounds__(256) void vq_sq(const float* __restrict__ x,
                                             const float* __restrict__ emb,
                                             float* __restrict__ x_sq,
                                             float* __restrict__ e_sq) {
  const int t = threadIdx.x;
  const int wave = t >> 6, l = t & 63;
  const int half = l >> 5, ll = l & 31;
  const int q = ll >> 3, j = ll & 7;
  const int row = blockIdx.x * 8 + wave * 2 + half;  // 0..16383
  const float* p =
      (row < N_ROWS) ? (x + (size_t)row * D_DIM)
                     : (emb + (size_t)(row - N_ROWS) * D_DIM);
  const float v0 = p[128 * q + j];
  float r = __fmul_rn(v0, v0);
#pragma unroll
  for (int i = 1; i < 16; ++i) {
    const float v = p[128 * q + 8 * i + j];
    r = __fadd_rn(r, __fmul_rn(v, v));
  }
  r = __fadd_rn(r, __shfl_xor(r, 1, 64));
  r = __fadd_rn(r, __shfl_xor(r, 2, 64));
  r = __fadd_rn(r, __shfl_xor(r, 4, 64));
  r = __fadd_rn(r, __shfl_xor(r, 8, 64));
  r = __fadd_rn(r, __shfl_xor(r, 16, 64));
  if (ll == 0) {
    if (row < N_ROWS) x_sq[row] = r;
    else e_sq[row - N_ROWS] = r;
  }
}

// ---------------------------------------------------------------------------
// Kernel 2: distance + argmin. R15 skeleton (32n x 256k, 256 thr, r=8 j=4,
// dd-chunk 16, scattered-row e-swizzle, 2-buffer stage-ahead, streaming
// XCD map, launch_bounds(256,2)) + x STAGED THROUGH LDS:
//
// R15 residual: 32 L3/HBM-cold s_load_dwordx4 (x) per chunk consumed inside
// compute -> first consumer stalls ~500-900cy, only 3.5 waves/SIMD to cover
// (15% idle). Now threads t<128 stage the 2 KB x-chunk (32 rows x 16 dd)
// with one global_load_lds each, alongside the e-stage; compute reads x as
// wave-uniform broadcast ds_read_b128 (same-addr = conflict-free). The
// existing stage(next) -> compute(cur) -> vmcnt(0) pipeline hides x latency
// under a full chunk of FMA. R13 proved this compute structure; its failure
// was the (256,4) cap-64 spill -- here cap 128 fits the ~110-reg set.
//
// LDS 2x16K (e) + 2x2K (x) = 36 KB -> 4 blocks/CU.
// e layout/swizzle per R15: 256 rows x 16 dd, P(r,q)=r*16+4*(q^((r>>1)&3)),
// lane l owns rows {l,l+64,l+128,l+192}; stage src quad (t&3)^((t>>3)&3).
// x layout: [32 rows][16 dd] linear; wave w reads rows w*8..w*8+7.
//
// FMA chain per output bit-identical to R3-R17: chunks ascend dd (16 each),
// accA = chunks 0..23 (dd<384), accB = 24..31, _rn ops, ev.x->w order.
// ---------------------------------------------------------------------------
__device__ __forceinline__ void compute_chunk16(const float* __restrict__ esb,
                                                const float* __restrict__ xsb,
                                                int lane,
                                                float (&acc)[8][4]) {
  const int lbase = lane * 16;       // e row l (16 floats/row)
  const int lm = (lane >> 1) & 3;    // swizzle hash, j-independent
#pragma unroll
  for (int g = 0; g < 4; ++g) {
    const float* p = esb + lbase + 4 * (g ^ lm);
    const float4 ev0 = *reinterpret_cast<const float4*>(p);         // row l
    const float4 ev1 = *reinterpret_cast<const float4*>(p + 1024);  // row l+64
    const float4 ev2 = *reinterpret_cast<const float4*>(p + 2048);  // row l+128
    const float4 ev3 = *reinterpret_cast<const float4*>(p + 3072);  // row l+192
#pragma unroll
    for (int r = 0; r < 8; ++r) {
      const float4 xv =
          *reinterpret_cast<const float4*>(xsb + r * 16 + 4 * g);  // broadcast
      float a0 = acc[r][0], a1 = acc[r][1], a2 = acc[r][2], a3 = acc[r][3];
      a0 = __fmaf_rn(xv.x, ev0.x, a0);
      a0 = __fmaf_rn(xv.y, ev0.y, a0);
      a0 = __fmaf_rn(xv.z, ev0.z, a0);
      a0 = __fmaf_rn(xv.w, ev0.w, a0);
      a1 = __fmaf_rn(xv.x, ev1.x, a1);
      a1 = __fmaf_rn(xv.y, ev1.y, a1);
      a1 = __fmaf_rn(xv.z, ev1.z, a1);
      a1 = __fmaf_rn(xv.w, ev1.w, a1);
      a2 = __fmaf_rn(xv.x, ev2.x, a2);
      a2 = __fmaf_rn(xv.y, ev2.y, a2);
      a2 = __fmaf_rn(xv.z, ev2.z, a2);
      a2 = __fmaf_rn(xv.w, ev2.w, a2);
      a3 = __fmaf_rn(xv.x, ev3.x, a3);
      a3 = __fmaf_rn(xv.y, ev3.y, a3);
      a3 = __fmaf_rn(xv.z, ev3.z, a3);
      a3 = __fmaf_rn(xv.w, ev3.w, a3);
      acc[r][0] = a0; acc[r][1] = a1; acc[r][2] = a2; acc[r][3] = a3;
    }
  }
}

// Stage one chunk: e = 16 KB (4 x 16-B loads/thread, R15 addressing);
// x = 2 KB (threads t<128: one 16-B load; row t>>2, quad t&3, linear dest).
#define STAGE(BUF, ESRC, XSRC)                                                 \
  do {                                                                         \
    __builtin_amdgcn_global_load_lds(                                          \
        (const __attribute__((address_space(1))) void*)(ESRC),                 \
        (__attribute__((address_space(3))) void*)(&es[BUF][4 * t]), 16, 0, 0); \
    __builtin_amdgcn_global_load_lds(                                          \
        (const __attribute__((address_space(1))) void*)((ESRC) + 64 * D_DIM),  \
        (__attribute__((address_space(3))) void*)(&es[BUF][4 * t + 1024]),     \
        16, 0, 0);                                                             \
    __builtin_amdgcn_global_load_lds(                                          \
        (const __attribute__((address_space(1))) void*)((ESRC) + 128 * D_DIM), \
        (__attribute__((address_space(3))) void*)(&es[BUF][4 * t + 2048]),     \
        16, 0, 0);                                                             \
    __builtin_amdgcn_global_load_lds(                                          \
        (const __attribute__((address_space(1))) void*)((ESRC) + 192 * D_DIM), \
        (__attribute__((address_space(3))) void*)(&es[BUF][4 * t + 3072]),     \
        16, 0, 0);                                                             \
    if (t < 128) {                                                             \
      __builtin_amdgcn_global_load_lds(                                        \
          (const __attribute__((address_space(1))) void*)(XSRC),               \
          (__attribute__((address_space(3))) void*)(&xs[BUF][4 * t]), 16, 0,   \
          0);                                                                  \
    }                                                                          \
  } while (0)

__global__ __launch_bounds__(256, 2) void vq_dist(
    const float* __restrict__ x, const float* __restrict__ e,
    const float* __restrict__ x_sq, const float* __restrict__ e_sq,
    u64* __restrict__ slots) {
  __shared__ float es[2][4096];  // e: 2 x 16 KB
  __shared__ float xs[2][512];   // x: 2 x 2 KB (32 rows x 16 dd)

  const int t = threadIdx.x;
  const int lane = t & 63;
  const int w = t >> 6;

  // Streaming XCD map (R14/R15-validated): XCD bx&7 owns 4 kb panels
  // (256k x 512d = 512 KB L2-hot), sweeps all 256 nb per panel.
  const int bx = blockIdx.x;
  const int swz = (bx & 7) * 1024 + (bx >> 3);
  const int kb = swz >> 8;    // 0..31
  const int nb = swz & 255;   // 0..255
  const int k0 = kb * 256;
  const int n0b = nb * 32;
  const int n0w = __builtin_amdgcn_readfirstlane(n0b + w * 8);

  // Hoisted per-thread stage source bases (chunk 0); advance 16/chunk.
  const float* esrc =
      e + (size_t)(k0 + (t >> 2)) * D_DIM + 4 * ((t & 3) ^ ((t >> 3) & 3));
  const float* xsrc = x + (size_t)(n0b + (t >> 2)) * D_DIM + 4 * (t & 3);

  // Wave's x slice inside xs: rows w*8..w*8+7 -> floats [w*128, w*128+128).
  const float* xsb0 = &xs[0][w * 128];
  const float* xsb1 = &xs[1][w * 128];

  float accA[8][4], accB[8][4];
#pragma unroll
  for (int r = 0; r < 8; ++r)
#pragma unroll
    for (int j = 0; j < 4; ++j) { accA[r][j] = 0.0f; accB[r][j] = 0.0f; }

  // Prologue: fill buffer 0 with chunk 0.
  STAGE(0, esrc, xsrc);
  asm volatile("s_waitcnt vmcnt(0)" ::: "memory");
  __syncthreads();

  // Phase A: chunks 0..23 (dd < 384).
#pragma unroll 1
  for (int c = 0; c < 24; ++c) {
    STAGE((c + 1) & 1, esrc + (c + 1) * 16, xsrc + (c + 1) * 16);
    compute_chunk16(&es[c & 1][0], (c & 1) ? xsb1 : xsb0, lane, accA);
    asm volatile("s_waitcnt vmcnt(0)" ::: "memory");
    __syncthreads();
  }
  // Phase B: chunks 24..31 (dd >= 384).
#pragma unroll 1
  for (int c = 24; c < 32; ++c) {
    if (c < 31) STAGE((c + 1) & 1, esrc + (c + 1) * 16, xsrc + (c + 1) * 16);
    compute_chunk16(&es[c & 1][0], (c & 1) ? xsb1 : xsb0, lane, accB);
    asm volatile("s_waitcnt vmcnt(0)" ::: "memory");
    __syncthreads();
  }

  // Epilogue: dist = fl(fl(x_sq - 2*dot) + e_sq); packed-key argmin.
  // Lane owns k = k0 + lane + 64*j (scattered ownership, matches LDS rows).
  const float4 xsqa = *reinterpret_cast<const float4*>(x_sq + n0w);
  const float4 xsqb = *reinterpret_cast<const float4*>(x_sq + n0w + 4);
  const float xsq[8] = {xsqa.x, xsqa.y, xsqa.z, xsqa.w,
                        xsqb.x, xsqb.y, xsqb.z, xsqb.w};
  const int klane = k0 + lane;
  const float esqv[4] = {e_sq[klane], e_sq[klane + 64], e_sq[klane + 128],
                         e_sq[klane + 192]};

#pragma unroll
  for (int r = 0; r < 8; ++r) {
    u64 best = ~0ULL;
#pragma unroll
    for (int j = 0; j < 4; ++j) {
      float dot = __fadd_rn(accA[r][j], accB[r][j]);
      float dist = __fadd_rn(__fsub_rn(xsq[r], __fmul_rn(2.0f, dot)), esqv[j]);
      unsigned int b = __float_as_uint(dist);
      unsigned int sb = (b & 0x80000000u) ? ~b : (b | 0x80000000u);
      u64 key = ((u64)sb << 32) | (unsigned)(klane + 64 * j);
      best = best < key ? best : key;
    }
#pragma unroll
    for (int off = 32; off > 0; off >>= 1) {
      u64 o = __shfl_xor((unsigned long long)best, off, 64);
      best = best < o ? best : o;
    }
    if (lane == 0) atomicMin(&slots[n0w + r], best);
  }
}

// ---------------------------------------------------------------------------
// Kernel 3: gather quantized rows (one wave per row), f32 outputs, loss
// partials into 256 hashed f64 buckets.
// ---------------------------------------------------------------------------
__global__ __launch_bounds__(256) void vq_out(
    const float* __restrict__ x, const float* __restrict__ e,
    const u64* __restrict__ slots, float* __restrict__ out_q,
    float* __restrict__ out_idx, double* __restrict__ loss_part) {
  const int t = threadIdx.x;
  const int w = t >> 6, lane = t & 63;
  const int n = blockIdx.x * 4 + w;
  const int idx = (int)(slots[n] & 0xFFFFFFFFULL);
  const float4* qr = (const float4*)(e + (size_t)idx * D_DIM);
  const float4* xr = (const float4*)(x + (size_t)n * D_DIM);
  float4* outr = (float4*)(out_q + (size_t)n * D_DIM);
  double s = 0.0;
#pragma unroll
  for (int i = 0; i < 2; ++i) {
    const int d4 = lane * 2 + i;
    float4 q = qr[d4];
    float4 xv = xr[d4];
    outr[d4] = q;
    double d0 = (double)xv.x - (double)q.x;
    double d1 = (double)xv.y - (double)q.y;
    double d2 = (double)xv.z - (double)q.z;
    double d3 = (double)xv.w - (double)q.w;
    s += d0 * d0 + d1 * d1 + d2 * d2 + d3 * d3;
  }
  for (int off = 32; off > 0; off >>= 1) s += __shfl_down(s, off, 64);
  if (lane == 0) {
    out_idx[n] = (float)idx;
    atomicAdd(&loss_part[(n * 37) & 255], s);
  }
}

__global__ void vq_loss(const double* __restrict__ loss_part,
                        float* __restrict__ out_s) {
  __shared__ double sm[256];
  const int t = threadIdx.x;
  sm[t] = loss_part[t];
  __syncthreads();
  for (int off = 128; off > 0; off >>= 1) {
    if (t < off) sm[t] += sm[t + off];
    __syncthreads();
  }
  if (t == 0) {
    double m = sm[0] / (double)(N_ROWS * D_DIM);
    out_s[0] = (float)(0.25 * m);
    out_s[1] = (float)m;
    out_s[2] = (float)(1.25 * m);
  }
}

extern "C" void kernel_launch(void* const* d_in, const int* in_sizes, int n_in,
                              void* d_out, int out_size, void* d_ws, size_t ws_size,
                              hipStream_t stream) {
  const float* x = (const float*)d_in[0];
  const float* emb = (const float*)d_in[1];
  float* out = (float*)d_out;

  // ws: [0,64K) u64 slots; [64K,96K) f32 x_sq; [96K,128K) f32 e_sq;
  //     [128K,130K) f64 loss_part[256]
  u64* slots = (u64*)d_ws;
  float* x_sq = (float*)((char*)d_ws + 65536);
  float* e_sq = (float*)((char*)d_ws + 98304);
  double* loss_part = (double*)((char*)d_ws + 131072);

  hipMemsetAsync(d_ws, 0xFF, 65536, stream);
  hipMemsetAsync(loss_part, 0, 256 * sizeof(double), stream);

  vq_sq<<<2048, 256, 0, stream>>>(x, emb, x_sq, e_sq);
  vq_dist<<<8192, 256, 0, stream>>>(x, emb, x_sq, e_sq, slots);
  vq_out<<<N_ROWS / 4, 256, 0, stream>>>(x, emb, slots, out,
                                         out + N_ROWS * D_DIM, loss_part);
  vq_loss<<<1, 256, 0, stream>>>(loss_part, out + N_ROWS * D_DIM + N_ROWS);
}

// Round 19
// 1003.604 us; speedup vs baseline: 1.0974x; 1.0974x over previous
//
#include <hip/hip_runtime.h>

#define N_ROWS 8192
#define K_CODES 8192
#define D_DIM 512

typedef unsigned long long u64;

// ---------------------------------------------------------------------------
// Kernel 1: x_sq / e_sq, wave-parallel, bit-exact numpy pairwise emulation
// (validated R9-R18). 32 lanes per row; shfl_xor tree = numpy's add order.
// ---------------------------------------------------------------------------
__global__ __launch_bounds__(256) void vq_sq(const float* __restrict__ x,
                                             const float* __restrict__ emb,
                                             float* __restrict__ x_sq,
                                             float* __restrict__ e_sq) {
  const int t = threadIdx.x;
  const int wave = t >> 6, l = t & 63;
  const int half = l >> 5, ll = l & 31;
  const int q = ll >> 3, j = ll & 7;
  const int row = blockIdx.x * 8 + wave * 2 + half;  // 0..16383
  const float* p =
      (row < N_ROWS) ? (x + (size_t)row * D_DIM)
                     : (emb + (size_t)(row - N_ROWS) * D_DIM);
  const float v0 = p[128 * q + j];
  float r = __fmul_rn(v0, v0);
#pragma unroll
  for (int i = 1; i < 16; ++i) {
    const float v = p[128 * q + 8 * i + j];
    r = __fadd_rn(r, __fmul_rn(v, v));
  }
  r = __fadd_rn(r, __shfl_xor(r, 1, 64));
  r = __fadd_rn(r, __shfl_xor(r, 2, 64));
  r = __fadd_rn(r, __shfl_xor(r, 4, 64));
  r = __fadd_rn(r, __shfl_xor(r, 8, 64));
  r = __fadd_rn(r, __shfl_xor(r, 16, 64));
  if (ll == 0) {
    if (row < N_ROWS) x_sq[row] = r;
    else e_sq[row - N_ROWS] = r;
  }
}

// ---------------------------------------------------------------------------
// Kernel 2: distance + argmin -- TRANSPOSED ROLES vs R15.
// Block = 256n x 32k (256 thr). Wave owns 8 k-rows (e = wave-uniform SMEM,
// L2-HOT: one 64 KB e-tile pinned per XCD, shared by all 32 concurrent
// blocks). Lanes own n: lane l owns n-rows {l, l+64, l+128, l+192} of the
// block's 256-row x-panel, staged per-chunk through global_load_lds
// (the latency-TOLERANT path; x is the cold stream -- R15 had it on
// latency-exposed s_loads, 600-900cy misses on the FMA critical path).
//
// Map: xcd=bx&7 owns kb in [xcd*32,xcd*32+32); np = inner sweep (32 blocks
// sharing one e-tile run concurrently on the XCD). x panels restage from
// L3 (16 MB working set, L3-resident). Predicted FETCH: 534 MB -> <100 MB.
//
// LDS x layout/swizzle = R15's e layout (validated): 256 rows x 16 dd,
// P(r,q)=r*16+4*(q^((r>>1)&3)); stage src quad (t&3)^((t>>3)&3), linear
// dest. Registers: acc 64 + xv 16 ~= 85 live (phase B) under (256,2)
// cap 128 -- same class R15 compiled to VGPR 64.
//
// FMA chain per output bit-identical to R3-R18: dd ascends (chunk c ->
// dd0=c*16, quad g, components 0..3), accA = chunks 0..23, accB = 24..31,
// _rn ops. e value is the (single legal) SGPR operand of each FMA.
// ---------------------------------------------------------------------------
__device__ __forceinline__ void compute_chunk16(const float* __restrict__ xsb,
                                                const float* __restrict__ ew,
                                                int dd0, int lane,
                                                float (&acc)[8][4]) {
  const int lbase = lane * 16;       // x row l (16 floats/row)
  const int lm = (lane >> 1) & 3;    // swizzle hash, j-independent
#pragma unroll
  for (int g = 0; g < 4; ++g) {
    const float* p = xsb + lbase + 4 * (g ^ lm);
    const float4 xv0 = *reinterpret_cast<const float4*>(p);         // row l
    const float4 xv1 = *reinterpret_cast<const float4*>(p + 1024);  // row l+64
    const float4 xv2 = *reinterpret_cast<const float4*>(p + 2048);  // row l+128
    const float4 xv3 = *reinterpret_cast<const float4*>(p + 3072);  // row l+192
#pragma unroll
    for (int r = 0; r < 8; ++r) {
      const float* eq = ew + r * D_DIM + dd0 + 4 * g;  // wave-uniform
      const float e0 = eq[0];
      const float e1 = eq[1];
      const float e2 = eq[2];
      const float e3 = eq[3];
      float a0 = acc[r][0], a1 = acc[r][1], a2 = acc[r][2], a3 = acc[r][3];
      a0 = __fmaf_rn(xv0.x, e0, a0);
      a0 = __fmaf_rn(xv0.y, e1, a0);
      a0 = __fmaf_rn(xv0.z, e2, a0);
      a0 = __fmaf_rn(xv0.w, e3, a0);
      a1 = __fmaf_rn(xv1.x, e0, a1);
      a1 = __fmaf_rn(xv1.y, e1, a1);
      a1 = __fmaf_rn(xv1.z, e2, a1);
      a1 = __fmaf_rn(xv1.w, e3, a1);
      a2 = __fmaf_rn(xv2.x, e0, a2);
      a2 = __fmaf_rn(xv2.y, e1, a2);
      a2 = __fmaf_rn(xv2.z, e2, a2);
      a2 = __fmaf_rn(xv2.w, e3, a2);
      a3 = __fmaf_rn(xv3.x, e0, a3);
      a3 = __fmaf_rn(xv3.y, e1, a3);
      a3 = __fmaf_rn(xv3.z, e2, a3);
      a3 = __fmaf_rn(xv3.w, e3, a3);
      acc[r][0] = a0; acc[r][1] = a1; acc[r][2] = a2; acc[r][3] = a3;
    }
  }
}

// Stage one 16 KB x-chunk (256 n-rows x 16 dd): thread t does I=0..3 loads.
// Dest float idx 4t + 1024I; src row (t>>2)+64I, quad (t&3)^((t>>3)&3).
#define STAGE(BUF, XSRC)                                                       \
  do {                                                                         \
    __builtin_amdgcn_global_load_lds(                                          \
        (const __attribute__((address_space(1))) void*)(XSRC),                 \
        (__attribute__((address_space(3))) void*)(&xs[BUF][4 * t]), 16, 0, 0); \
    __builtin_amdgcn_global_load_lds(                                          \
        (const __attribute__((address_space(1))) void*)((XSRC) + 64 * D_DIM),  \
        (__attribute__((address_space(3))) void*)(&xs[BUF][4 * t + 1024]),     \
        16, 0, 0);                                                             \
    __builtin_amdgcn_global_load_lds(                                          \
        (const __attribute__((address_space(1))) void*)((XSRC) + 128 * D_DIM), \
        (__attribute__((address_space(3))) void*)(&xs[BUF][4 * t + 2048]),     \
        16, 0, 0);                                                             \
    __builtin_amdgcn_global_load_lds(                                          \
        (const __attribute__((address_space(1))) void*)((XSRC) + 192 * D_DIM), \
        (__attribute__((address_space(3))) void*)(&xs[BUF][4 * t + 3072]),     \
        16, 0, 0);                                                             \
  } while (0)

__global__ __launch_bounds__(256, 2) void vq_dist(
    const float* __restrict__ x, const float* __restrict__ e,
    const float* __restrict__ x_sq, const float* __restrict__ e_sq,
    u64* __restrict__ slots) {
  __shared__ float xs[2][4096];  // x: 2 x 16 KB
  __shared__ u64 rowmin[256];    // per-n block-local argmin

  const int t = threadIdx.x;
  const int lane = t & 63;
  const int w = t >> 6;

  // Map: XCD bx&7 owns kb in [xcd*32, xcd*32+32); for each kb, 32 np-blocks
  // run concurrently sharing the 64 KB e-tile (L2-hot). x panels (512 KB)
  // restage from L3 (16 MB total, L3-resident after first sweep).
  const int bx = blockIdx.x;
  const int xcd = bx & 7;
  const int s = bx >> 3;               // 0..1023
  const int kb = xcd * 32 + (s >> 5);  // 0..255
  const int np = s & 31;               // 0..31
  const int k0 = kb * 32;
  const int n0b = np * 256;

  const int kw = __builtin_amdgcn_readfirstlane(k0 + w * 8);
  const float* ew = e + (size_t)kw * D_DIM;

  // Hoisted per-thread x stage source base (chunk 0); advance 16/chunk.
  const float* xsrc =
      x + (size_t)(n0b + (t >> 2)) * D_DIM + 4 * ((t & 3) ^ ((t >> 3) & 3));

  rowmin[t] = ~0ULL;  // covered by the prologue __syncthreads

  float accA[8][4], accB[8][4];
#pragma unroll
  for (int r = 0; r < 8; ++r)
#pragma unroll
    for (int j = 0; j < 4; ++j) { accA[r][j] = 0.0f; accB[r][j] = 0.0f; }

  // Prologue: fill buffer 0 with chunk 0.
  STAGE(0, xsrc);
  asm volatile("s_waitcnt vmcnt(0)" ::: "memory");
  __syncthreads();

  // Phase A: chunks 0..23 (dd < 384).
#pragma unroll 1
  for (int c = 0; c < 24; ++c) {
    STAGE((c + 1) & 1, xsrc + (c + 1) * 16);
    compute_chunk16(&xs[c & 1][0], ew, c * 16, lane, accA);
    asm volatile("s_waitcnt vmcnt(0)" ::: "memory");
    __syncthreads();
  }
  // Phase B: chunks 24..31 (dd >= 384).
#pragma unroll 1
  for (int c = 24; c < 32; ++c) {
    if (c < 31) STAGE((c + 1) & 1, xsrc + (c + 1) * 16);
    compute_chunk16(&xs[c & 1][0], ew, c * 16, lane, accB);
    asm volatile("s_waitcnt vmcnt(0)" ::: "memory");
    __syncthreads();
  }

  // Epilogue: dist = fl(fl(x_sq - 2*dot) + e_sq); packed-key argmin.
  // Thread owns (8 k = kw..kw+7) x (4 n = n0b+lane+64j). Reduce over k
  // locally (k ascending -> first-index tie-break preserved), then LDS
  // rowmin per n, then one global atomicMin per n-row.
  const float xsqv[4] = {x_sq[n0b + lane], x_sq[n0b + lane + 64],
                         x_sq[n0b + lane + 128], x_sq[n0b + lane + 192]};
  float esq[8];
#pragma unroll
  for (int r = 0; r < 8; ++r) esq[r] = e_sq[kw + r];

#pragma unroll
  for (int j = 0; j < 4; ++j) {
    u64 best = ~0ULL;
#pragma unroll
    for (int r = 0; r < 8; ++r) {
      float dot = __fadd_rn(accA[r][j], accB[r][j]);
      float dist = __fadd_rn(__fsub_rn(xsqv[j], __fmul_rn(2.0f, dot)), esq[r]);
      unsigned int b = __float_as_uint(dist);
      unsigned int sb = (b & 0x80000000u) ? ~b : (b | 0x80000000u);
      u64 key = ((u64)sb << 32) | (unsigned)(kw + r);
      best = best < key ? best : key;
    }
    atomicMin(&rowmin[lane + 64 * j], best);
  }
  __syncthreads();
  atomicMin(&slots[n0b + t], rowmin[t]);
}

// ---------------------------------------------------------------------------
// Kernel 3: gather quantized rows (one wave per row), f32 outputs, loss
// partials into 256 hashed f64 buckets.
// ---------------------------------------------------------------------------
__global__ __launch_bounds__(256) void vq_out(
    const float* __restrict__ x, const float* __restrict__ e,
    const u64* __restrict__ slots, float* __restrict__ out_q,
    float* __restrict__ out_idx, double* __restrict__ loss_part) {
  const int t = threadIdx.x;
  const int w = t >> 6, lane = t & 63;
  const int n = blockIdx.x * 4 + w;
  const int idx = (int)(slots[n] & 0xFFFFFFFFULL);
  const float4* qr = (const float4*)(e + (size_t)idx * D_DIM);
  const float4* xr = (const float4*)(x + (size_t)n * D_DIM);
  float4* outr = (float4*)(out_q + (size_t)n * D_DIM);
  double s = 0.0;
#pragma unroll
  for (int i = 0; i < 2; ++i) {
    const int d4 = lane * 2 + i;
    float4 q = qr[d4];
    float4 xv = xr[d4];
    outr[d4] = q;
    double d0 = (double)xv.x - (double)q.x;
    double d1 = (double)xv.y - (double)q.y;
    double d2 = (double)xv.z - (double)q.z;
    double d3 = (double)xv.w - (double)q.w;
    s += d0 * d0 + d1 * d1 + d2 * d2 + d3 * d3;
  }
  for (int off = 32; off > 0; off >>= 1) s += __shfl_down(s, off, 64);
  if (lane == 0) {
    out_idx[n] = (float)idx;
    atomicAdd(&loss_part[(n * 37) & 255], s);
  }
}

__global__ void vq_loss(const double* __restrict__ loss_part,
                        float* __restrict__ out_s) {
  __shared__ double sm[256];
  const int t = threadIdx.x;
  sm[t] = loss_part[t];
  __syncthreads();
  for (int off = 128; off > 0; off >>= 1) {
    if (t < off) sm[t] += sm[t + off];
    __syncthreads();
  }
  if (t == 0) {
    double m = sm[0] / (double)(N_ROWS * D_DIM);
    out_s[0] = (float)(0.25 * m);
    out_s[1] = (float)m;
    out_s[2] = (float)(1.25 * m);
  }
}

extern "C" void kernel_launch(void* const* d_in, const int* in_sizes, int n_in,
                              void* d_out, int out_size, void* d_ws, size_t ws_size,
                              hipStream_t stream) {
  const float* x = (const float*)d_in[0];
  const float* emb = (const float*)d_in[1];
  float* out = (float*)d_out;

  // ws: [0,64K) u64 slots; [64K,96K) f32 x_sq; [96K,128K) f32 e_sq;
  //     [128K,130K) f64 loss_part[256]
  u64* slots = (u64*)d_ws;
  float* x_sq = (float*)((char*)d_ws + 65536);
  float* e_sq = (float*)((char*)d_ws + 98304);
  double* loss_part = (double*)((char*)d_ws + 131072);

  hipMemsetAsync(d_ws, 0xFF, 65536, stream);
  hipMemsetAsync(loss_part, 0, 256 * sizeof(double), stream);

  vq_sq<<<2048, 256, 0, stream>>>(x, emb, x_sq, e_sq);
  vq_dist<<<8192, 256, 0, stream>>>(x, emb, x_sq, e_sq, slots);
  vq_out<<<N_ROWS / 4, 256, 0, stream>>>(x, emb, slots, out,
                                         out + N_ROWS * D_DIM, loss_part);
  vq_loss<<<1, 256, 0, stream>>>(loss_part, out + N_ROWS * D_DIM + N_ROWS);
}

// Round 20
// 874.273 us; speedup vs baseline: 1.2597x; 1.1479x over previous
//
#include <hip/hip_runtime.h>

#define N_ROWS 8192
#define K_CODES 8192
#define D_DIM 512

typedef unsigned long long u64;

// ---------------------------------------------------------------------------
// Kernel 1: x_sq / e_sq, wave-parallel, bit-exact numpy pairwise emulation
// (validated R9-R19). 32 lanes per row; shfl_xor tree = numpy's add order.
// ---------------------------------------------------------------------------
__global__ __launch_bounds__(256) void vq_sq(const float* __restrict__ x,
                                             const float* __restrict__ emb,
                                             float* __restrict__ x_sq,
                                             float* __restrict__ e_sq) {
  const int t = threadIdx.x;
  const int wave = t >> 6, l = t & 63;
  const int half = l >> 5, ll = l & 31;
  const int q = ll >> 3, j = ll & 7;
  const int row = blockIdx.x * 8 + wave * 2 + half;  // 0..16383
  const float* p =
      (row < N_ROWS) ? (x + (size_t)row * D_DIM)
                     : (emb + (size_t)(row - N_ROWS) * D_DIM);
  const float v0 = p[128 * q + j];
  float r = __fmul_rn(v0, v0);
#pragma unroll
  for (int i = 1; i < 16; ++i) {
    const float v = p[128 * q + 8 * i + j];
    r = __fadd_rn(r, __fmul_rn(v, v));
  }
  r = __fadd_rn(r, __shfl_xor(r, 1, 64));
  r = __fadd_rn(r, __shfl_xor(r, 2, 64));
  r = __fadd_rn(r, __shfl_xor(r, 4, 64));
  r = __fadd_rn(r, __shfl_xor(r, 8, 64));
  r = __fadd_rn(r, __shfl_xor(r, 16, 64));
  if (ll == 0) {
    if (row < N_ROWS) x_sq[row] = r;
    else e_sq[row - N_ROWS] = r;
  }
}

// ---------------------------------------------------------------------------
// Kernel 2: distance + argmin. R15 EXACT RESTORE (best: 875us total).
// Tile 32n x 256k (256 thr, 4 waves), r=8 j=4 micro-tile, dd-chunk 16,
// LDS 2 x 16 KB dbuf, stage(next)->compute(cur)->vmcnt(0)+barrier.
//
// Why this configuration won (R5-R19 evidence):
// - j=4: 1 wave-uniform x s_load per 16 FMA-instr; x FETCH at streaming
//   minimum 534 MB (R14).
// - Scattered k-row ownership {l, l+64, l+128, l+192}: full 32-bank LDS
//   spread, conflicts at structural floor 6.7e7 (R15; R14's 4l layout
//   was 16-way = 2.01e8).
// - acc 64 floats + (256,2) cap 128: VGPR 64, zero spill, zero AGPR
//   shuffle (R5/R6/R7/R9/R13 all lost to allocator pathologies).
// - 256-thr blocks: 3-4 independent barrier groups/CU (R12's +5%).
// - Streaming XCD map: e-panel L2-hot, x streamed 32x; every L2-clever
//   alternative (R11 supergroup, R19 role-swap) thrashed L3/HBM.
// Failed structural variants: r4xj4 (R16, LDS-traffic 2x), counted-vmcnt
// 3-buf (R17, VGPR 108 -> occ 23%), x-through-LDS (R13/R18, VGPR blowup).
//
// FMA chain per output bit-identical to R3-R19: chunks ascend dd (16 each),
// accA = chunks 0..23 (dd<384), accB = 24..31, _rn ops, ev.x->w order.
// ---------------------------------------------------------------------------
__device__ __forceinline__ void compute_chunk16(const float* __restrict__ esb,
                                                const float* __restrict__ xw,
                                                int dd0, int lane,
                                                float (&acc)[8][4]) {
  const int lbase = lane * 16;       // row l (16 floats/row)
  const int lm = (lane >> 1) & 3;    // swizzle hash, j-independent
#pragma unroll
  for (int g = 0; g < 4; ++g) {
    const float* p = esb + lbase + 4 * (g ^ lm);
    const float4 ev0 = *reinterpret_cast<const float4*>(p);         // row l
    const float4 ev1 = *reinterpret_cast<const float4*>(p + 1024);  // row l+64
    const float4 ev2 = *reinterpret_cast<const float4*>(p + 2048);  // row l+128
    const float4 ev3 = *reinterpret_cast<const float4*>(p + 3072);  // row l+192
#pragma unroll
    for (int r = 0; r < 8; ++r) {
      const float4 xv =
          *reinterpret_cast<const float4*>(xw + r * D_DIM + dd0 + 4 * g);
      float a0 = acc[r][0], a1 = acc[r][1], a2 = acc[r][2], a3 = acc[r][3];
      a0 = __fmaf_rn(xv.x, ev0.x, a0);
      a0 = __fmaf_rn(xv.y, ev0.y, a0);
      a0 = __fmaf_rn(xv.z, ev0.z, a0);
      a0 = __fmaf_rn(xv.w, ev0.w, a0);
      a1 = __fmaf_rn(xv.x, ev1.x, a1);
      a1 = __fmaf_rn(xv.y, ev1.y, a1);
      a1 = __fmaf_rn(xv.z, ev1.z, a1);
      a1 = __fmaf_rn(xv.w, ev1.w, a1);
      a2 = __fmaf_rn(xv.x, ev2.x, a2);
      a2 = __fmaf_rn(xv.y, ev2.y, a2);
      a2 = __fmaf_rn(xv.z, ev2.z, a2);
      a2 = __fmaf_rn(xv.w, ev2.w, a2);
      a3 = __fmaf_rn(xv.x, ev3.x, a3);
      a3 = __fmaf_rn(xv.y, ev3.y, a3);
      a3 = __fmaf_rn(xv.z, ev3.z, a3);
      a3 = __fmaf_rn(xv.w, ev3.w, a3);
      acc[r][0] = a0; acc[r][1] = a1; acc[r][2] = a2; acc[r][3] = a3;
    }
  }
}

// Stage one 16 KB chunk (256 rows x 16 dd): thread t does I=0..3 16-B loads.
// Dest float idx 4t + 1024I; src row (t>>2)+64I, quad (t&3)^((t>>3)&3).
#define STAGE(BUF, ESRC)                                                       \
  do {                                                                         \
    __builtin_amdgcn_global_load_lds(                                          \
        (const __attribute__((address_space(1))) void*)(ESRC),                 \
        (__attribute__((address_space(3))) void*)(&es[BUF][4 * t]), 16, 0, 0); \
    __builtin_amdgcn_global_load_lds(                                          \
        (const __attribute__((address_space(1))) void*)((ESRC) + 64 * D_DIM),  \
        (__attribute__((address_space(3))) void*)(&es[BUF][4 * t + 1024]),     \
        16, 0, 0);                                                             \
    __builtin_amdgcn_global_load_lds(                                          \
        (const __attribute__((address_space(1))) void*)((ESRC) + 128 * D_DIM), \
        (__attribute__((address_space(3))) void*)(&es[BUF][4 * t + 2048]),     \
        16, 0, 0);                                                             \
    __builtin_amdgcn_global_load_lds(                                          \
        (const __attribute__((address_space(1))) void*)((ESRC) + 192 * D_DIM), \
        (__attribute__((address_space(3))) void*)(&es[BUF][4 * t + 3072]),     \
        16, 0, 0);                                                             \
  } while (0)

__global__ __launch_bounds__(256, 2) void vq_dist(
    const float* __restrict__ x, const float* __restrict__ e,
    const float* __restrict__ x_sq, const float* __restrict__ e_sq,
    u64* __restrict__ slots) {
  __shared__ float es[2][4096];  // 2 x 16 KB

  const int t = threadIdx.x;
  const int lane = t & 63;
  const int w = t >> 6;

  // Streaming XCD map: XCD bx&7 owns 4 kb panels (256k x 512d = 512 KB
  // L2-hot), sweeps all 256 nb per panel; x streams 32 passes (L3-backed).
  const int bx = blockIdx.x;
  const int swz = (bx & 7) * 1024 + (bx >> 3);
  const int kb = swz >> 8;    // 0..31
  const int nb = swz & 255;   // 0..255
  const int k0 = kb * 256;
  const int n0w = __builtin_amdgcn_readfirstlane(nb * 32 + w * 8);
  const float* xw = x + (size_t)n0w * D_DIM;

  // Hoisted per-thread stage source base (chunk 0); advance 16 floats/chunk.
  const float* esrc =
      e + (size_t)(k0 + (t >> 2)) * D_DIM + 4 * ((t & 3) ^ ((t >> 3) & 3));

  float accA[8][4], accB[8][4];
#pragma unroll
  for (int r = 0; r < 8; ++r)
#pragma unroll
    for (int j = 0; j < 4; ++j) { accA[r][j] = 0.0f; accB[r][j] = 0.0f; }

  // Prologue: fill buffer 0 with chunk 0.
  STAGE(0, esrc);
  asm volatile("s_waitcnt vmcnt(0)" ::: "memory");
  __syncthreads();

  // Phase A: chunks 0..23 (dd < 384).
#pragma unroll 1
  for (int c = 0; c < 24; ++c) {
    STAGE((c + 1) & 1, esrc + (c + 1) * 16);
    compute_chunk16(&es[c & 1][0], xw, c * 16, lane, accA);
    asm volatile("s_waitcnt vmcnt(0)" ::: "memory");
    __syncthreads();
  }
  // Phase B: chunks 24..31 (dd >= 384).
#pragma unroll 1
  for (int c = 24; c < 32; ++c) {
    if (c < 31) STAGE((c + 1) & 1, esrc + (c + 1) * 16);
    compute_chunk16(&es[c & 1][0], xw, c * 16, lane, accB);
    asm volatile("s_waitcnt vmcnt(0)" ::: "memory");
    __syncthreads();
  }

  // Epilogue: dist = fl(fl(x_sq - 2*dot) + e_sq); packed-key argmin.
  // Lane owns k = k0 + lane + 64*j (scattered ownership, matches LDS rows).
  const float4 xsqa = *reinterpret_cast<const float4*>(x_sq + n0w);
  const float4 xsqb = *reinterpret_cast<const float4*>(x_sq + n0w + 4);
  const float xsq[8] = {xsqa.x, xsqa.y, xsqa.z, xsqa.w,
                        xsqb.x, xsqb.y, xsqb.z, xsqb.w};
  const int klane = k0 + lane;
  const float esqv[4] = {e_sq[klane], e_sq[klane + 64], e_sq[klane + 128],
                         e_sq[klane + 192]};

#pragma unroll
  for (int r = 0; r < 8; ++r) {
    u64 best = ~0ULL;
#pragma unroll
    for (int j = 0; j < 4; ++j) {
      float dot = __fadd_rn(accA[r][j], accB[r][j]);
      float dist = __fadd_rn(__fsub_rn(xsq[r], __fmul_rn(2.0f, dot)), esqv[j]);
      unsigned int b = __float_as_uint(dist);
      unsigned int sb = (b & 0x80000000u) ? ~b : (b | 0x80000000u);
      u64 key = ((u64)sb << 32) | (unsigned)(klane + 64 * j);
      best = best < key ? best : key;
    }
#pragma unroll
    for (int off = 32; off > 0; off >>= 1) {
      u64 o = __shfl_xor((unsigned long long)best, off, 64);
      best = best < o ? best : o;
    }
    if (lane == 0) atomicMin(&slots[n0w + r], best);
  }
}

// ---------------------------------------------------------------------------
// Kernel 3: gather quantized rows (one wave per row), f32 outputs, loss
// partials into 256 hashed f64 buckets.
// ---------------------------------------------------------------------------
__global__ __launch_bounds__(256) void vq_out(
    const float* __restrict__ x, const float* __restrict__ e,
    const u64* __restrict__ slots, float* __restrict__ out_q,
    float* __restrict__ out_idx, double* __restrict__ loss_part) {
  const int t = threadIdx.x;
  const int w = t >> 6, lane = t & 63;
  const int n = blockIdx.x * 4 + w;
  const int idx = (int)(slots[n] & 0xFFFFFFFFULL);
  const float4* qr = (const float4*)(e + (size_t)idx * D_DIM);
  const float4* xr = (const float4*)(x + (size_t)n * D_DIM);
  float4* outr = (float4*)(out_q + (size_t)n * D_DIM);
  double s = 0.0;
#pragma unroll
  for (int i = 0; i < 2; ++i) {
    const int d4 = lane * 2 + i;
    float4 q = qr[d4];
    float4 xv = xr[d4];
    outr[d4] = q;
    double d0 = (double)xv.x - (double)q.x;
    double d1 = (double)xv.y - (double)q.y;
    double d2 = (double)xv.z - (double)q.z;
    double d3 = (double)xv.w - (double)q.w;
    s += d0 * d0 + d1 * d1 + d2 * d2 + d3 * d3;
  }
  for (int off = 32; off > 0; off >>= 1) s += __shfl_down(s, off, 64);
  if (lane == 0) {
    out_idx[n] = (float)idx;
    atomicAdd(&loss_part[(n * 37) & 255], s);
  }
}

__global__ void vq_loss(const double* __restrict__ loss_part,
                        float* __restrict__ out_s) {
  __shared__ double sm[256];
  const int t = threadIdx.x;
  sm[t] = loss_part[t];
  __syncthreads();
  for (int off = 128; off > 0; off >>= 1) {
    if (t < off) sm[t] += sm[t + off];
    __syncthreads();
  }
  if (t == 0) {
    double m = sm[0] / (double)(N_ROWS * D_DIM);
    out_s[0] = (float)(0.25 * m);
    out_s[1] = (float)m;
    out_s[2] = (float)(1.25 * m);
  }
}

extern "C" void kernel_launch(void* const* d_in, const int* in_sizes, int n_in,
                              void* d_out, int out_size, void* d_ws, size_t ws_size,
                              hipStream_t stream) {
  const float* x = (const float*)d_in[0];
  const float* emb = (const float*)d_in[1];
  float* out = (float*)d_out;

  // ws: [0,64K) u64 slots; [64K,96K) f32 x_sq; [96K,128K) f32 e_sq;
  //     [128K,130K) f64 loss_part[256]
  u64* slots = (u64*)d_ws;
  float* x_sq = (float*)((char*)d_ws + 65536);
  float* e_sq = (float*)((char*)d_ws + 98304);
  double* loss_part = (double*)((char*)d_ws + 131072);

  hipMemsetAsync(d_ws, 0xFF, 65536, stream);
  hipMemsetAsync(loss_part, 0, 256 * sizeof(double), stream);

  vq_sq<<<2048, 256, 0, stream>>>(x, emb, x_sq, e_sq);
  vq_dist<<<8192, 256, 0, stream>>>(x, emb, x_sq, e_sq, slots);
  vq_out<<<N_ROWS / 4, 256, 0, stream>>>(x, emb, slots, out,
                                         out + N_ROWS * D_DIM, loss_part);
  vq_loss<<<1, 256, 0, stream>>>(loss_part, out + N_ROWS * D_DIM + N_ROWS);
}